// Round 5
// baseline (428.556 us; speedup 1.0000x reference)
//
#include <hip/hip_runtime.h>
#include <math.h>

#define SEQL 784
#define HIDN 512
#define OUTD 10

// DPP mov: lanes not selected by row_mask, or with invalid source (bound_ctrl),
// yield 0. Single-use results feeding a TIED VOP2 (v_fmac/v_add) fold into
// v_{add,fmac}_f32_dpp.
template<int CTRL, int RM>
__device__ __forceinline__ float dpp0(float v) {
    int r = __builtin_amdgcn_update_dpp(0, __builtin_bit_cast(int, v),
                                        CTRL, RM, 0xF, true);
    return __builtin_bit_cast(float, r);
}

// M[i][o] = sum_j C1[j][i] * W[j][o]  (512 x 10): logits = h2f @ M + b.
__global__ __launch_bounds__(256) void compute_M(const float* __restrict__ C1,
                                                 const float* __restrict__ W,
                                                 float* __restrict__ M) {
    __shared__ float Ws[HIDN * OUTD];
    __shared__ float red[4][64][OUTD];
    const int lane = threadIdx.x & 63, w = threadIdx.x >> 6;
    const int i = blockIdx.x * 64 + lane;
    for (int idx = threadIdx.x; idx < HIDN * OUTD; idx += 256) Ws[idx] = W[idx];
    __syncthreads();
    float acc[OUTD];
#pragma unroll
    for (int o = 0; o < OUTD; ++o) acc[o] = 0.f;
    for (int j = w * 128; j < w * 128 + 128; ++j) {
        float cv = C1[j * HIDN + i];
#pragma unroll
        for (int o = 0; o < OUTD; ++o) acc[o] = fmaf(cv, Ws[j * OUTD + o], acc[o]);
    }
#pragma unroll
    for (int o = 0; o < OUTD; ++o) red[w][lane][o] = acc[o];
    __syncthreads();
    if (w == 0) {
#pragma unroll
        for (int o = 0; o < OUTD; ++o)
            M[i * OUTD + o] = (red[0][lane][o] + red[1][lane][o]) +
                              (red[2][lane][o] + red[3][lane][o]);
    }
}

// Per-lane constants for one layer-stream (8 hidden elems per lane).
struct Consts {
    float mE2[8], P2[8], G2[8], Psp[8], K_[8], C0d2[8];
    float ac[6], bc[6];
    float PiL;
};

// One scalar SSM step: H <- G2 * tanh(solve((I+cA)h + du*P)).
//  r~-fold: FT_j == -1568*mE2_j exactly, so seeding r~ = -1568*du makes
//  in_j = fma(mE2_j, r~_{j-1}, H_j) carry the du*P term for free; one fma
//  recovers true r for the scan.  sigma-rescaled local solve (s = PiL*g);
//  w8 coeff mE2_j*Pi_{j-1} == K_j.  tanh tail pairs adjacent j for the rcp:
//  rp = rcp(ep_a*ep_b); tanh_a = 1 - ep_b*rp (ep = (E+1)/2).
template<bool PART>
static __device__ __forceinline__ float sstep(float (&H)[8], float du,
                                              const Consts& C) {
    // ---- pass 1: per-lane local (r~, sigma)
    float w8[8];
    float rt = -1568.0f * du;                 // r~_{-1}
    float in0 = fmaf(C.mE2[0], rt, H[0]);
    w8[0] = in0;
    float g = C.Psp[0] * in0;
    rt = fmaf(C.P2[0], H[0], rt);
#pragma unroll
    for (int j = 1; j < 8; ++j) {
        float in_ = fmaf(C.mE2[j], rt, H[j]);
        w8[j] = fmaf(C.K_[j], g, in_);        // uses g BEFORE update j
        g = fmaf(C.Psp[j], in_, g);
        rt = fmaf(C.P2[j], H[j], rt);
    }
    float r = fmaf(1568.0f, du, rt);          // recover true r
    float s = C.PiL * g;                      // true local s for the scan

    // ---- wave affine scan via DPP (tied fmacs, foldable)
#define LVLS(CTRL, RM, L) {                                                  \
        s = fmaf(dpp0<CTRL, RM>(s), C.bc[L], s);                             \
        s = fmaf(dpp0<CTRL, RM>(r), C.ac[L], s);                             \
        r += dpp0<CTRL, RM>(r); }
    LVLS(0x111, 0xF, 0)   // row_shr:1
    LVLS(0x112, 0xF, 1)   // row_shr:2
    LVLS(0x114, 0xF, 2)   // row_shr:4
    LVLS(0x118, 0xF, 3)   // row_shr:8
    LVLS(0x142, 0xA, 4)   // row_bcast:15 -> rows 1,3
    LVLS(0x143, 0xC, 5)   // row_bcast:31 -> rows 2,3
#undef LVLS
    float t = r + s;
    float S0 = dpp0<0x138, 0xF>(t);           // exclusive (wave_shr:1), lane0=0

    // ---- pass 2 (breadth-first): yy off S0, exp2, half-ep, paired rcp, tanh
    float yy[8], ep[8];
#pragma unroll
    for (int j = 0; j < 8; ++j) yy[j] = fmaf(C.K_[j], S0, w8[j]);
#pragma unroll
    for (int j = 0; j < 8; ++j)
        ep[j] = fmaf(__builtin_amdgcn_exp2f(yy[j]), 0.5f, 0.5f);
#pragma unroll
    for (int q = 0; q < 4; ++q) {
        float rp = __builtin_amdgcn_rcpf(ep[2*q] * ep[2*q+1]);
        float n0 = -C.G2[2*q]     * rp;
        float n1 = -C.G2[2*q + 1] * rp;
        H[2*q]     = fmaf(ep[2*q + 1], n0, C.G2[2*q]);
        H[2*q + 1] = fmaf(ep[2*q],     n1, C.G2[2*q + 1]);
    }
    float part = 0.f;
    if (PART) {
#pragma unroll
        for (int j = 0; j < 8; ++j) part = fmaf(C.C0d2[j], H[j], part);
        part += dpp0<0x111, 0xF>(part);
        part += dpp0<0x112, 0xF>(part);
        part += dpp0<0x114, 0xF>(part);
        part += dpp0<0x118, 0xF>(part);
        part += dpp0<0x142, 0xA>(part);
        part += dpp0<0x143, 0xC>(part);       // lane63 holds full sum
    }
    return part;
}

// TLP layer-split: 512 threads = 8 waves; waves 0-3 run layer 1 of rows
// blockIdx*4+{0..3} (producers), waves 4-7 run layer 2 of the same rows
// (consumers) lagging 8 steps.  y0 flows through a 16-slot LDS ring per row:
// phases of 8 steps fenced by one block barrier; consumer phase p reads the
// batch producer wrote in phase p-1 (two broadcast ds_read_b128).  2048 waves
// total -> 2 waves/SIMD: one wave's VALU fills the other's scan/trans stalls.
__global__ __launch_bounds__(512, 2) void ssm_main(const float* __restrict__ x,
                                                   const float* __restrict__ C0,
                                                   const float* __restrict__ Mmat,
                                                   const float* __restrict__ bias,
                                                   float* __restrict__ out) {
    const int tid = threadIdx.x;
    const int wave = tid >> 6;
    const int lane = tid & 63;
    const int slot = wave & 3;                // row within block
    const int role = wave >> 2;               // 0 = layer1, 1 = layer2
    const int row = blockIdx.x * 4 + slot;

    __shared__ __align__(16) float xs[4][SEQL + 8];  // row stride 792 (16B ok)
    __shared__ __align__(16) float ring[4][16];

    const float DEL = 1.0f / 784.0f;
    {
        const float4* __restrict__ xv =
            (const float4*)(x + (size_t)blockIdx.x * 4 * SEQL);
#pragma unroll
        for (int it = 0; it < 2; ++it) {
            int idx = tid + it * 512;                 // float4 index, < 784
            if (idx < 4 * (SEQL / 4)) {
                float4 v = xv[idx];
                int rr = idx / (SEQL / 4);
                int cc = (idx % (SEQL / 4)) * 4;
                float4 w;
                w.x = DEL * v.x; w.y = DEL * v.y;
                w.z = DEL * v.z; w.w = DEL * v.w;
                *(float4*)&xs[rr][cc] = w;
            }
        }
    }
    __syncthreads();

    // ---- per-lane constants (fp64 -> fp32, matching reference f64 A_d/B_d)
    const double cd = 1.0 / 1568.0;            // step/2
    const double F = 2.0 * 1.4426950408889634; // 2*log2(e) fold for exp2
    Consts C;
    double apD = 0.0, bpD = 1.0;               // in-lane partial (alpha, beta)
    double Aprod = 1.0;                        // prod of a_m, m < j
#pragma unroll
    for (int j = 0; j < 8; ++j) {
        int i = lane * 8 + j;
        double Pd = sqrt(1.0 + 2.0 * (double)i);
        double dd = 1.0 + cd * (double)(i + 1);
        double fd = 1.0 / dd;
        double ad = (1.0 - cd * (double)i) * fd;
        double mEd = -cd * Pd * fd;
        double ed = Pd * mEd;                   // -cP^2/d ; note 1 - a + e == 0
        double Gd = (1.0 - cd * (double)(i + 1)) * fd;
        double G2d = F * Gd;
        apD = ad * apD + ed;
        bpD = ad * bpD;
        C.P2[j]  = (float)(Pd / G2d);           // r advances on H = G2*h
        C.G2[j]  = (float)G2d;
        C.mE2[j] = (float)(F * mEd);            // FT_j == -1568*mE2_j
        C.K_[j]  = (float)(F * mEd * Aprod);    // mE2_j * prod_{m<j} a_m
        C.Psp[j] = (float)((Pd / F) / (Aprod * ad)); // Ps_j / Pi_j
        Aprod *= ad;
        C.C0d2[j] = (float)((double)DEL * (double)C0[i] / G2d);
    }
    C.PiL = (float)Aprod;                       // Pi_7
    // ---- scan-level constants mirroring the DPP segment structure
    {
        double al = apD, be = bpD;
        int rl = lane & 15;
#pragma unroll
        for (int L = 0; L < 4; ++L) {          // row_shr:1,2,4,8 (row-capped)
            int d = 1 << L;
            C.ac[L] = (float)al; C.bc[L] = (float)be;
            double pa = __shfl_up(al, d, 64);
            double pb = __shfl_up(be, d, 64);
            if (rl >= d) { al += be * pa; be *= pb; }
        }
        C.ac[4] = (float)al; C.bc[4] = (float)be;  // row_bcast:15 -> rows 1,3
        {
            int src = (lane & 32) + 15;
            double pa = __shfl(al, src, 64);
            double pb = __shfl(be, src, 64);
            if (lane & 16) { al += be * pa; be *= pb; }
        }
        C.ac[5] = (float)al; C.bc[5] = (float)be;  // row_bcast:31 -> rows 2,3
        {
            double pa = __shfl(al, 31, 64);
            double pb = __shfl(be, 31, 64);
            if (lane >= 32) { al += be * pa; be *= pb; }
        }
    }

    float H[8];
#pragma unroll
    for (int j = 0; j < 8; ++j) H[j] = 0.f;

    float* ringp = ring[slot];
    const float* xrow = xs[slot];

    // 99 phases x 8 steps.  Producer active p in [0,97]; consumer in [1,98].
    for (int p = 0; p < 99; ++p) {
        if (role == 0) {
            if (p < 98) {
                const float4* up = (const float4*)&xrow[p * 8];
                float4 u0 = up[0], u1 = up[1];
                float ub[8] = {u0.x, u0.y, u0.z, u0.w, u1.x, u1.y, u1.z, u1.w};
                int base = (p * 8) & 15;
#pragma unroll
                for (int b = 0; b < 8; ++b) {
                    float part = sstep<true>(H, ub[b], C);
                    if (lane == 63) ringp[base + b] = part;
                }
            }
        } else {
            if (p >= 1) {
                const float4* yp = (const float4*)&ringp[((p - 1) * 8) & 15];
                float4 y0v = yp[0], y1v = yp[1];
                float yb[8] = {y0v.x, y0v.y, y0v.z, y0v.w,
                               y1v.x, y1v.y, y1v.z, y1v.w};
#pragma unroll
                for (int b = 0; b < 8; ++b) sstep<false>(H, yb[b], C);
            }
        }
        __syncthreads();
    }

    // ---- epilogue (layer-2 waves): logits[row] = h2 @ M + b
    if (role == 1) {
        float acc[OUTD];
#pragma unroll
        for (int o = 0; o < OUTD; ++o) acc[o] = 0.f;
#pragma unroll
        for (int j = 0; j < 8; ++j) {
            float hv = H[j] / C.G2[j];           // one-time unscale
            int i = lane * 8 + j;
#pragma unroll
            for (int o = 0; o < OUTD; ++o)
                acc[o] = fmaf(hv, Mmat[i * OUTD + o], acc[o]);
        }
#pragma unroll
        for (int o = 0; o < OUTD; ++o) {
#pragma unroll
            for (int d = 32; d; d >>= 1) acc[o] += __shfl_xor(acc[o], d, 64);
        }
        if (lane == 0) {
#pragma unroll
            for (int o = 0; o < OUTD; ++o) out[row * OUTD + o] = acc[o] + bias[o];
        }
    }
}

extern "C" void kernel_launch(void* const* d_in, const int* in_sizes, int n_in,
                              void* d_out, int out_size, void* d_ws, size_t ws_size,
                              hipStream_t stream) {
    const float* x  = (const float*)d_in[0];  // (1024, 784)
    const float* C0 = (const float*)d_in[1];  // (1, 512)
    const float* C1 = (const float*)d_in[2];  // (512, 512)
    const float* W  = (const float*)d_in[3];  // (512, 10)
    const float* b  = (const float*)d_in[4];  // (10,)
    float* M = (float*)d_ws;                  // 512*10 fp32 scratch

    compute_M<<<dim3(8), dim3(256), 0, stream>>>(C1, W, M);
    ssm_main<<<dim3(256), dim3(512), 0, stream>>>(x, C0, M, b, (float*)d_out);
}

// Round 6
// 376.051 us; speedup vs baseline: 1.1396x; 1.1396x over previous
//
#include <hip/hip_runtime.h>
#include <math.h>

#define SEQL 784
#define HIDN 512
#define OUTD 10

typedef float v2 __attribute__((ext_vector_type(2)));

// DPP mov: lanes not selected by row_mask, or with invalid source (bound_ctrl),
// yield 0. Single-use results feeding a TIED VOP2 (v_fmac/v_add) fold into
// v_{add,fmac}_f32_dpp; VOP3 v_fma_f32 cannot take DPP on CDNA, so the scan
// is phrased as two serial fmac-shaped updates per value.
template<int CTRL, int RM>
__device__ __forceinline__ float dpp0(float v) {
    int r = __builtin_amdgcn_update_dpp(0, __builtin_bit_cast(int, v),
                                        CTRL, RM, 0xF, true);
    return __builtin_bit_cast(float, r);
}
__device__ __forceinline__ v2 sp(float v) { v2 r; r.x = v; r.y = v; return r; }
__device__ __forceinline__ v2 vfma(v2 a, v2 b, v2 c) {
    return __builtin_elementwise_fma(a, b, c);   // -> v_pk_fma_f32 (full-rate)
}

// M[i][o] = sum_j C1[j][i] * W[j][o]  (512 x 10): logits = h2f @ M + b.
__global__ __launch_bounds__(256) void compute_M(const float* __restrict__ C1,
                                                 const float* __restrict__ W,
                                                 float* __restrict__ M) {
    __shared__ float Ws[HIDN * OUTD];
    __shared__ float red[4][64][OUTD];
    const int lane = threadIdx.x & 63, w = threadIdx.x >> 6;
    const int i = blockIdx.x * 64 + lane;
    for (int idx = threadIdx.x; idx < HIDN * OUTD; idx += 256) Ws[idx] = W[idx];
    __syncthreads();
    float acc[OUTD];
#pragma unroll
    for (int o = 0; o < OUTD; ++o) acc[o] = 0.f;
    for (int j = w * 128; j < w * 128 + 128; ++j) {
        float cv = C1[j * HIDN + i];
#pragma unroll
        for (int o = 0; o < OUTD; ++o) acc[o] = fmaf(cv, Ws[j * OUTD + o], acc[o]);
    }
#pragma unroll
    for (int o = 0; o < OUTD; ++o) red[w][lane][o] = acc[o];
    __syncthreads();
    if (w == 0) {
#pragma unroll
        for (int o = 0; o < OUTD; ++o)
            M[i * OUTD + o] = (red[0][lane][o] + red[1][lane][o]) +
                              (red[2][lane][o] + red[3][lane][o]);
    }
}

// Wave affine scan via DPP; two tied fmacs per value per level (bc-term
// first: consumes OLD s; r updated after s so ac-term sees OLD r).
#define LVL(CTRL, RM, L) {                                                   \
        s.x = fmaf(dpp0<CTRL, RM>(s.x), bc[L], s.x);                         \
        s.x = fmaf(dpp0<CTRL, RM>(r.x), ac[L], s.x);                         \
        s.y = fmaf(dpp0<CTRL, RM>(s.y), bc[L], s.y);                         \
        s.y = fmaf(dpp0<CTRL, RM>(r.y), ac[L], s.y);                         \
        r.x += dpp0<CTRL, RM>(r.x);                                          \
        r.y += dpp0<CTRL, RM>(r.y); }

// One SSM step on G2-scaled state H = G2*h.
//  r~-fold: FT_j == -1568*mE2_j exactly, so seeding r~ = -1568*du makes
//  in_j = fma(mE2_j, r~_{j-1}, H_j) carry the du*P term for free; one pk fma
//  recovers true r for the scan.  sigma-rescaled local solve (s = PiL*sg);
//  w8 coeff mE2_j*Pi_{j-1} == K_j; r advances with P2 = P/G2 so r keeps its
//  TRUE value (scan constants unchanged).
//  tanh tail: ep=(E+1)/2; rp=rcp(ep.x*ep.y); hn-pair comes out component-
//  SWAPPED; callers alternate layout parity (even: (L1,L2)->(L2,L1), odd
//  swaps du packing and PSEL).  H regenerated as fma(ep_sw, -G2*rp, G2).
template<int PSEL>
static __device__ __forceinline__ float do_step(
        v2 (&H)[8], v2 du,
        const float (&P2)[8], const float (&G2)[8], const float (&mE2)[8],
        const float (&K_)[8], const float (&Psp)[8],
        const float (&C0d2)[8], float PiL,
        const float (&ac)[6], const float (&bc)[6]) {
    // ---- pass 1: per-lane local (r~, sigma); j=0 peeled (r~ = -1568*du)
    v2 w8[8];
    v2 rt = sp(-1568.0f) * du;
    v2 in0 = vfma(sp(mE2[0]), rt, H[0]);
    w8[0] = in0;
    v2 sg = sp(Psp[0]) * in0;
    rt = vfma(sp(P2[0]), H[0], rt);
#pragma unroll
    for (int j = 1; j < 8; ++j) {
        v2 in_ = vfma(sp(mE2[j]), rt, H[j]);
        w8[j] = vfma(sp(K_[j]), sg, in_);        // uses sg BEFORE update j
        sg = vfma(sp(Psp[j]), in_, sg);
        rt = vfma(sp(P2[j]), H[j], rt);
    }
    v2 r = vfma(sp(1568.0f), du, rt);            // recover true r
    v2 s = sp(PiL) * sg;                         // true local s for the scan

    LVL(0x111, 0xF, 0)   // row_shr:1
    LVL(0x112, 0xF, 1)   // row_shr:2
    LVL(0x114, 0xF, 2)   // row_shr:4
    LVL(0x118, 0xF, 3)   // row_shr:8
    LVL(0x142, 0xA, 4)   // row_bcast:15 -> rows 1,3
    LVL(0x143, 0xC, 5)   // row_bcast:31 -> rows 2,3

    // exclusive incoming state: S0 = shift1(r + s)  (lane0 = 0)
    v2 t = r + s, S0;
    S0.x = dpp0<0x138, 0xF>(t.x);  S0.y = dpp0<0x138, 0xF>(t.y);

    // ---- pass 2 (breadth-first): yy off S0, exp2, half-ep, rcp, H-rebuild
    v2 yy[8], ep[8];
    float pm[8], rp[8];
#pragma unroll
    for (int j = 0; j < 8; ++j)
        yy[j] = vfma(sp(K_[j]), S0, w8[j]);      // independent per j
#pragma unroll
    for (int j = 0; j < 8; ++j) {
        v2 E;
        E.x = __builtin_amdgcn_exp2f(yy[j].x);
        E.y = __builtin_amdgcn_exp2f(yy[j].y);
        ep[j] = vfma(E, sp(0.5f), sp(0.5f));     // (E+1)/2
    }
#pragma unroll
    for (int j = 0; j < 8; ++j) pm[j] = ep[j].x * ep[j].y;
#pragma unroll
    for (int j = 0; j < 8; ++j) rp[j] = __builtin_amdgcn_rcpf(pm[j]);
    float part = 0.f;
#pragma unroll
    for (int j = 0; j < 8; ++j) {
        float nt = -G2[j] * rp[j];               // fold G2 into tanh fixup
        v2 hn = vfma(ep[j], sp(nt), sp(G2[j]));  // G2 * swapped tanh pair
        H[j] = hn;
        part = fmaf(C0d2[j], PSEL ? hn.y : hn.x, part);
    }
    // y0 reduce: 2 iterations of slack before consumption
    part += dpp0<0x111, 0xF>(part);
    part += dpp0<0x112, 0xF>(part);
    part += dpp0<0x114, 0xF>(part);
    part += dpp0<0x118, 0xF>(part);
    part += dpp0<0x142, 0xA>(part);
    part += dpp0<0x143, 0xC>(part);
    return part;
}

// One wave per batch row; lane owns 8 hidden elems; layers 1/2 ride in .x/.y
// of packed fp32 (parity-alternating order), layer 2 lagging TWO steps.
// 98 phases x 8 steps: u's batched as two ds_read_b128 per phase; 2 tail
// steps (u = 0) peeled so H stops at exactly 786 updates.
__global__ __launch_bounds__(256, 1) void ssm_main(const float* __restrict__ x,
                                                   const float* __restrict__ C0,
                                                   const float* __restrict__ Mmat,
                                                   const float* __restrict__ bias,
                                                   float* __restrict__ out) {
    const int tid = threadIdx.x;
    const int wave = tid >> 6;
    const int lane = tid & 63;
    const int row = blockIdx.x * 4 + wave;

    __shared__ __align__(16) float xs[4][SEQL + 8];   // row stride 792 (16B aligned)

    const float DEL = 1.0f / 784.0f;
    {
        const float4* __restrict__ xv =
            (const float4*)(x + (size_t)blockIdx.x * 4 * SEQL);
#pragma unroll
        for (int it = 0; it < 4; ++it) {
            int idx = tid + it * 256;                 // float4 index, need < 784
            if (idx < SEQL) {
                float4 v = xv[idx];
                int r = idx / (SEQL / 4);
                int c = (idx % (SEQL / 4)) * 4;
                float4 w;
                w.x = DEL * v.x; w.y = DEL * v.y;
                w.z = DEL * v.z; w.w = DEL * v.w;
                *(float4*)&xs[r][c] = w;
            }
        }
    }
    if (tid < 32) xs[tid >> 3][SEQL + (tid & 7)] = 0.f;
    __syncthreads();

    // ---- per-lane constants (fp64 -> fp32, matching reference f64 A_d/B_d)
    const double cd = 1.0 / 1568.0;            // step/2
    const double F = 2.0 * 1.4426950408889634; // 2*log2(e) fold for exp2
    float P2[8], G2[8], mE2[8], C0d2[8], K_[8], Psp[8], PiL;
    double apD = 0.0, bpD = 1.0;               // in-lane partial (alpha, beta)
    double Aprod = 1.0;                        // prod of a_m, m < j
#pragma unroll
    for (int j = 0; j < 8; ++j) {
        int i = lane * 8 + j;
        double Pd = sqrt(1.0 + 2.0 * (double)i);
        double dd = 1.0 + cd * (double)(i + 1);
        double fd = 1.0 / dd;
        double ad = (1.0 - cd * (double)i) * fd;
        double mEd = -cd * Pd * fd;
        double ed = Pd * mEd;                   // -cP^2/d ; note 1 - a + e == 0
        double Gd = (1.0 - cd * (double)(i + 1)) * fd;
        double G2d = F * Gd;
        apD = ad * apD + ed;
        bpD = ad * bpD;
        P2[j]  = (float)(Pd / G2d);             // r advances on H = G2*h
        G2[j]  = (float)G2d;
        mE2[j] = (float)(F * mEd);              // FT_j == -1568*mE2_j
        K_[j]  = (float)(F * mEd * Aprod);      // mE2_j * prod_{m<j} a_m
        Psp[j] = (float)((Pd / F) / (Aprod * ad)); // Ps_j / Pi_j
        Aprod *= ad;
        C0d2[j] = (float)((double)DEL * (double)C0[i] / G2d);
    }
    PiL = (float)Aprod;                         // Pi_7
    // ---- scan-level constants mirroring the DPP segment structure
    float ac[6], bc[6];
    {
        double al = apD, be = bpD;
        int rl = lane & 15;
#pragma unroll
        for (int L = 0; L < 4; ++L) {          // row_shr:1,2,4,8 (row-capped)
            int d = 1 << L;
            ac[L] = (float)al; bc[L] = (float)be;
            double pa = __shfl_up(al, d, 64);
            double pb = __shfl_up(be, d, 64);
            if (rl >= d) { al += be * pa; be *= pb; }
        }
        ac[4] = (float)al; bc[4] = (float)be;  // row_bcast:15 -> rows 1,3
        {
            int src = (lane & 32) + 15;
            double pa = __shfl(al, src, 64);
            double pb = __shfl(be, src, 64);
            if (lane & 16) { al += be * pa; be *= pb; }
        }
        ac[5] = (float)al; bc[5] = (float)be;  // row_bcast:31 -> rows 2,3
        {
            double pa = __shfl(al, 31, 64);
            double pb = __shfl(be, 31, 64);
            if (lane >= 32) { al += be * pa; be *= pb; }
        }
    }

    v2 H[8];
#pragma unroll
    for (int j = 0; j < 8; ++j) H[j] = sp(0.f);

    float y0_d1 = 0.f, y0_d2 = 0.f;  // y0 pipeline regs (layer-2 lag = 2)
    const float* xrow = xs[wave];

    for (int p = 0; p < 98; ++p) {
        const float4* up = (const float4*)&xrow[p * 8];
        float4 u0 = up[0], u1v = up[1];
        float ub[8] = {u0.x, u0.y, u0.z, u0.w, u1v.x, u1v.y, u1v.z, u1v.w};
#pragma unroll
        for (int q = 0; q < 4; ++q) {
            {   // even step: H in (L1,L2) order; produces (L2,L1); y0 from .y
                v2 du; du.x = ub[2 * q]; du.y = y0_d2;
                float part = do_step<1>(H, du, P2, G2, mE2, K_, Psp, C0d2, PiL,
                                        ac, bc);
                y0_d2 = y0_d1;
                y0_d1 = __builtin_bit_cast(float,
                          __builtin_amdgcn_readlane(__builtin_bit_cast(int, part), 63));
            }
            {   // odd step: H in (L2,L1) order; produces (L1,L2); y0 from .x
                v2 du; du.x = y0_d2; du.y = ub[2 * q + 1];
                float part = do_step<0>(H, du, P2, G2, mE2, K_, Psp, C0d2, PiL,
                                        ac, bc);
                y0_d2 = y0_d1;
                y0_d1 = __builtin_bit_cast(float,
                          __builtin_amdgcn_readlane(__builtin_bit_cast(int, part), 63));
            }
        }
    }
    {   // tail steps 784 (even) and 785 (odd): u = 0 (pad region)
        v2 du; du.x = 0.f; du.y = y0_d2;
        float part = do_step<1>(H, du, P2, G2, mE2, K_, Psp, C0d2, PiL, ac, bc);
        y0_d2 = y0_d1;
        y0_d1 = __builtin_bit_cast(float,
                  __builtin_amdgcn_readlane(__builtin_bit_cast(int, part), 63));
        (void)part;
    }
    {
        v2 du; du.x = y0_d2; du.y = 0.f;
        do_step<0>(H, du, P2, G2, mE2, K_, Psp, C0d2, PiL, ac, bc);
    }

    // ---- epilogue: logits[row] = h2_final @ M + b (M direct from global/L2)
    // (total steps 786 is even, so H ends in (L1,L2) order: H.y = G2*h_layer2)
    float acc[OUTD];
#pragma unroll
    for (int o = 0; o < OUTD; ++o) acc[o] = 0.f;
#pragma unroll
    for (int j = 0; j < 8; ++j) {
        float hv = H[j].y / G2[j];               // one-time unscale
        int i = lane * 8 + j;
#pragma unroll
        for (int o = 0; o < OUTD; ++o)
            acc[o] = fmaf(hv, Mmat[i * OUTD + o], acc[o]);
    }
#pragma unroll
    for (int o = 0; o < OUTD; ++o) {
#pragma unroll
        for (int d = 32; d; d >>= 1) acc[o] += __shfl_xor(acc[o], d, 64);
    }
    if (lane == 0) {
#pragma unroll
        for (int o = 0; o < OUTD; ++o) out[row * OUTD + o] = acc[o] + bias[o];
    }
}

extern "C" void kernel_launch(void* const* d_in, const int* in_sizes, int n_in,
                              void* d_out, int out_size, void* d_ws, size_t ws_size,
                              hipStream_t stream) {
    const float* x  = (const float*)d_in[0];  // (1024, 784)
    const float* C0 = (const float*)d_in[1];  // (1, 512)
    const float* C1 = (const float*)d_in[2];  // (512, 512)
    const float* W  = (const float*)d_in[3];  // (512, 10)
    const float* b  = (const float*)d_in[4];  // (10,)
    float* M = (float*)d_ws;                  // 512*10 fp32 scratch

    compute_M<<<dim3(8), dim3(256), 0, stream>>>(C1, W, M);
    ssm_main<<<dim3(256), dim3(256), 0, stream>>>(x, C0, M, b, (float*)d_out);
}

// Round 7
// 356.993 us; speedup vs baseline: 1.2005x; 1.0534x over previous
//
#include <hip/hip_runtime.h>
#include <math.h>

#define SEQL 784
#define HIDN 512
#define OUTD 10

typedef float v2 __attribute__((ext_vector_type(2)));

// DPP mov: lanes not selected by row_mask, or with invalid source (bound_ctrl),
// yield 0. Single-use results feeding a TIED VOP2 (v_fmac/v_add) fold into
// v_{add,fmac}_f32_dpp; VOP3 v_fma_f32 cannot take DPP on CDNA, so the scan
// is phrased as two serial fmac-shaped updates per value.
template<int CTRL, int RM>
__device__ __forceinline__ float dpp0(float v) {
    int r = __builtin_amdgcn_update_dpp(0, __builtin_bit_cast(int, v),
                                        CTRL, RM, 0xF, true);
    return __builtin_bit_cast(float, r);
}
__device__ __forceinline__ v2 sp(float v) { v2 r; r.x = v; r.y = v; return r; }
__device__ __forceinline__ v2 vfma(v2 a, v2 b, v2 c) {
    return __builtin_elementwise_fma(a, b, c);   // -> v_pk_fma_f32 (full-rate)
}

// M[i][o] = sum_j C1[j][i] * W[j][o]  (512 x 10): logits = h2f @ M + b.
__global__ __launch_bounds__(256) void compute_M(const float* __restrict__ C1,
                                                 const float* __restrict__ W,
                                                 float* __restrict__ M) {
    __shared__ float Ws[HIDN * OUTD];
    __shared__ float red[4][64][OUTD];
    const int lane = threadIdx.x & 63, w = threadIdx.x >> 6;
    const int i = blockIdx.x * 64 + lane;
    for (int idx = threadIdx.x; idx < HIDN * OUTD; idx += 256) Ws[idx] = W[idx];
    __syncthreads();
    float acc[OUTD];
#pragma unroll
    for (int o = 0; o < OUTD; ++o) acc[o] = 0.f;
    for (int j = w * 128; j < w * 128 + 128; ++j) {
        float cv = C1[j * HIDN + i];
#pragma unroll
        for (int o = 0; o < OUTD; ++o) acc[o] = fmaf(cv, Ws[j * OUTD + o], acc[o]);
    }
#pragma unroll
    for (int o = 0; o < OUTD; ++o) red[w][lane][o] = acc[o];
    __syncthreads();
    if (w == 0) {
#pragma unroll
        for (int o = 0; o < OUTD; ++o)
            M[i * OUTD + o] = (red[0][lane][o] + red[1][lane][o]) +
                              (red[2][lane][o] + red[3][lane][o]);
    }
}

// Wave affine scan via DPP; two tied fmacs per value per level (bc-term
// first: consumes OLD s; r updated after s so ac-term sees OLD r).
#define LVL(CTRL, RM, L) {                                                   \
        s.x = fmaf(dpp0<CTRL, RM>(s.x), bc[L], s.x);                         \
        s.x = fmaf(dpp0<CTRL, RM>(r.x), ac[L], s.x);                         \
        s.y = fmaf(dpp0<CTRL, RM>(s.y), bc[L], s.y);                         \
        s.y = fmaf(dpp0<CTRL, RM>(r.y), ac[L], s.y);                         \
        r.x += dpp0<CTRL, RM>(r.x);                                          \
        r.y += dpp0<CTRL, RM>(r.y); }

// Trans/VALU-fused SSM step (iteration k).  The j-loop interleaves, per j:
//   B(k-1): yy_j = K_j*S0 + w8_j; E = exp2(yy); ep = (E+1)/2; rp = rcp(ep.x*ep.y)
//   A(k)  : H_j(k-1) = pk_fma(ep, -G2*rp, G2)   (component-swapped tanh pair)
//           part(k-1) += C0d2*H_layer1 ; pass1: in_, w8(k), sg, rt chains.
// 3 trans + ~10 VALU per j-body, 8 independent bodies -> the in-order issue
// stream keeps the VALU fed while the quarter-rate trans pipe drains (the
// old breadth-first exp2/rcp blocks left the VALU idle ~200 cy/step).
//   r~-fold: FT_j == -1568*mE2_j exactly (rt seeded with -1568*du).
//   sigma-rescale: s = PiL*sg, w8 coeff mE2_j*Pi_{j-1} == K_j.
// Deferred-H also collapses the y0 pipeline to ONE reg with exact lag 2:
// y0cur = part(k-1) is set at step k and consumed as du at step k+1
// (layer2 stream at iteration k executes its step k-2).
// Init w8 = 0, S0 = 0 gives yy = 0 -> ep = 1, rp = 1 -> H(-1) = 0 exactly.
template<int PAR>
static __device__ __forceinline__ void fstep(
        v2 (&w8)[8], v2& S0, float& y0cur, float u,
        const float (&P2)[8], const float (&G2)[8], const float (&mE2)[8],
        const float (&K_)[8], const float (&Psp)[8],
        const float (&C0d2)[8], float PiL,
        const float (&ac)[6], const float (&bc)[6]) {
    v2 du;
    if (PAR) { du.x = y0cur; du.y = u; } else { du.x = u; du.y = y0cur; }
    v2 rt = sp(-1568.0f) * du;
    v2 sg = sp(0.f);
    float part = 0.f;
#pragma unroll
    for (int j = 0; j < 8; ++j) {
        // ---- B(k-1), index j: finish previous step's tanh inputs
        v2 yy = vfma(sp(K_[j]), S0, w8[j]);
        v2 E;
        E.x = __builtin_amdgcn_exp2f(yy.x);
        E.y = __builtin_amdgcn_exp2f(yy.y);
        v2 ep = vfma(E, sp(0.5f), sp(0.5f));       // (E+1)/2
        float rp = __builtin_amdgcn_rcpf(ep.x * ep.y);
        // ---- A(k), index j: materialize H_j(k-1), dot-partial, pass 1
        float nt = -G2[j] * rp;
        v2 Hj = vfma(ep, sp(nt), sp(G2[j]));       // swapped tanh pair * G2
        float hl1 = PAR ? Hj.y : Hj.x;             // layer-1 component
        part = fmaf(C0d2[j], hl1, part);
        v2 in_ = vfma(sp(mE2[j]), rt, Hj);
        w8[j] = (j == 0) ? in_ : vfma(sp(K_[j]), sg, in_);  // sg BEFORE update
        sg = (j == 0) ? sp(Psp[0]) * in_ : vfma(sp(Psp[j]), in_, sg);
        rt = vfma(sp(P2[j]), Hj, rt);
    }
    v2 r = vfma(sp(1568.0f), du, rt);              // recover true r
    v2 s = sp(PiL) * sg;                           // true local s for the scan

    // part-reduce (part = y0(k-1)): independent DPP chain, interleaves with
    // the scan below; consumed only at step k+1's du.
    part += dpp0<0x111, 0xF>(part);
    part += dpp0<0x112, 0xF>(part);
    part += dpp0<0x114, 0xF>(part);
    part += dpp0<0x118, 0xF>(part);
    part += dpp0<0x142, 0xA>(part);
    part += dpp0<0x143, 0xC>(part);

    LVL(0x111, 0xF, 0)   // row_shr:1
    LVL(0x112, 0xF, 1)   // row_shr:2
    LVL(0x114, 0xF, 2)   // row_shr:4
    LVL(0x118, 0xF, 3)   // row_shr:8
    LVL(0x142, 0xA, 4)   // row_bcast:15 -> rows 1,3
    LVL(0x143, 0xC, 5)   // row_bcast:31 -> rows 2,3

    v2 t = r + s;
    S0.x = dpp0<0x138, 0xF>(t.x);                  // exclusive: lane0 = 0
    S0.y = dpp0<0x138, 0xF>(t.y);
    y0cur = __builtin_bit_cast(float,
              __builtin_amdgcn_readlane(__builtin_bit_cast(int, part), 63));
}

// One wave per batch row; lane owns 8 hidden elems; layers 1/2 ride in .x/.y
// of packed fp32 (parity-alternating order), layer 2 lagging TWO steps.
// 98 phases x 8 steps (u batched as two ds_read_b128), then 2 pad steps
// (u = 0), then a tail-B materializing the final layer-2 state.
__global__ __launch_bounds__(256, 1) void ssm_main(const float* __restrict__ x,
                                                   const float* __restrict__ C0,
                                                   const float* __restrict__ Mmat,
                                                   const float* __restrict__ bias,
                                                   float* __restrict__ out) {
    const int tid = threadIdx.x;
    const int wave = tid >> 6;
    const int lane = tid & 63;
    const int row = blockIdx.x * 4 + wave;

    __shared__ __align__(16) float xs[4][SEQL + 8];   // row stride 792 (16B aligned)

    const float DEL = 1.0f / 784.0f;
    {
        const float4* __restrict__ xv =
            (const float4*)(x + (size_t)blockIdx.x * 4 * SEQL);
#pragma unroll
        for (int it = 0; it < 4; ++it) {
            int idx = tid + it * 256;                 // float4 index, need < 784
            if (idx < SEQL) {
                float4 v = xv[idx];
                int r = idx / (SEQL / 4);
                int c = (idx % (SEQL / 4)) * 4;
                float4 w;
                w.x = DEL * v.x; w.y = DEL * v.y;
                w.z = DEL * v.z; w.w = DEL * v.w;
                *(float4*)&xs[r][c] = w;
            }
        }
    }
    if (tid < 32) xs[tid >> 3][SEQL + (tid & 7)] = 0.f;
    __syncthreads();

    // ---- per-lane constants (fp64 -> fp32, matching reference f64 A_d/B_d)
    const double cd = 1.0 / 1568.0;            // step/2
    const double F = 2.0 * 1.4426950408889634; // 2*log2(e) fold for exp2
    float P2[8], G2[8], mE2[8], C0d2[8], K_[8], Psp[8], PiL;
    double apD = 0.0, bpD = 1.0;               // in-lane partial (alpha, beta)
    double Aprod = 1.0;                        // prod of a_m, m < j
#pragma unroll
    for (int j = 0; j < 8; ++j) {
        int i = lane * 8 + j;
        double Pd = sqrt(1.0 + 2.0 * (double)i);
        double dd = 1.0 + cd * (double)(i + 1);
        double fd = 1.0 / dd;
        double ad = (1.0 - cd * (double)i) * fd;
        double mEd = -cd * Pd * fd;
        double ed = Pd * mEd;                   // -cP^2/d ; note 1 - a + e == 0
        double Gd = (1.0 - cd * (double)(i + 1)) * fd;
        double G2d = F * Gd;
        apD = ad * apD + ed;
        bpD = ad * bpD;
        P2[j]  = (float)(Pd / G2d);             // r advances on H = G2*h
        G2[j]  = (float)G2d;
        mE2[j] = (float)(F * mEd);              // FT_j == -1568*mE2_j
        K_[j]  = (float)(F * mEd * Aprod);      // mE2_j * prod_{m<j} a_m
        Psp[j] = (float)((Pd / F) / (Aprod * ad)); // Ps_j / Pi_j
        Aprod *= ad;
        C0d2[j] = (float)((double)DEL * (double)C0[i] / G2d);
    }
    PiL = (float)Aprod;                         // Pi_7
    // ---- scan-level constants mirroring the DPP segment structure
    float ac[6], bc[6];
    {
        double al = apD, be = bpD;
        int rl = lane & 15;
#pragma unroll
        for (int L = 0; L < 4; ++L) {          // row_shr:1,2,4,8 (row-capped)
            int d = 1 << L;
            ac[L] = (float)al; bc[L] = (float)be;
            double pa = __shfl_up(al, d, 64);
            double pb = __shfl_up(be, d, 64);
            if (rl >= d) { al += be * pa; be *= pb; }
        }
        ac[4] = (float)al; bc[4] = (float)be;  // row_bcast:15 -> rows 1,3
        {
            int src = (lane & 32) + 15;
            double pa = __shfl(al, src, 64);
            double pb = __shfl(be, src, 64);
            if (lane & 16) { al += be * pa; be *= pb; }
        }
        ac[5] = (float)al; bc[5] = (float)be;  // row_bcast:31 -> rows 2,3
        {
            double pa = __shfl(al, 31, 64);
            double pb = __shfl(be, 31, 64);
            if (lane >= 32) { al += be * pa; be *= pb; }
        }
    }

    v2 w8[8], S0 = sp(0.f);
#pragma unroll
    for (int j = 0; j < 8; ++j) w8[j] = sp(0.f);
    float y0cur = 0.f;
    const float* xrow = xs[wave];

    for (int p = 0; p < 98; ++p) {
        const float4* up = (const float4*)&xrow[p * 8];
        float4 u0 = up[0], u1v = up[1];
        float ub[8] = {u0.x, u0.y, u0.z, u0.w, u1v.x, u1v.y, u1v.z, u1v.w};
#pragma unroll
        for (int q = 0; q < 4; ++q) {
            fstep<0>(w8, S0, y0cur, ub[2 * q],     P2, G2, mE2, K_, Psp,
                     C0d2, PiL, ac, bc);
            fstep<1>(w8, S0, y0cur, ub[2 * q + 1], P2, G2, mE2, K_, Psp,
                     C0d2, PiL, ac, bc);
        }
    }
    // pad steps k = 784 (even), 785 (odd): u = 0
    fstep<0>(w8, S0, y0cur, 0.f, P2, G2, mE2, K_, Psp, C0d2, PiL, ac, bc);
    fstep<1>(w8, S0, y0cur, 0.f, P2, G2, mE2, K_, Psp, C0d2, PiL, ac, bc);

    // ---- tail-B: materialize final layer-2 state from (S0, w8) of step 785.
    // A(785) was odd-parity: streams (.x = L2, .y = L1); the swapped tanh
    // pair puts layer-2 = 1 - rp*ep.y (unscaled; G2 cancels in the dot).
    float hv[8];
#pragma unroll
    for (int j = 0; j < 8; ++j) {
        v2 yy = vfma(sp(K_[j]), S0, w8[j]);
        v2 E;
        E.x = __builtin_amdgcn_exp2f(yy.x);
        E.y = __builtin_amdgcn_exp2f(yy.y);
        v2 ep = vfma(E, sp(0.5f), sp(0.5f));
        float rp = __builtin_amdgcn_rcpf(ep.x * ep.y);
        hv[j] = fmaf(-rp, ep.y, 1.0f);         // tanh of the .x (L2) stream
    }

    // ---- epilogue: logits[row] = h2_final @ M + b (M direct from global/L2)
    float acc[OUTD];
#pragma unroll
    for (int o = 0; o < OUTD; ++o) acc[o] = 0.f;
#pragma unroll
    for (int j = 0; j < 8; ++j) {
        int i = lane * 8 + j;
#pragma unroll
        for (int o = 0; o < OUTD; ++o)
            acc[o] = fmaf(hv[j], Mmat[i * OUTD + o], acc[o]);
    }
#pragma unroll
    for (int o = 0; o < OUTD; ++o) {
#pragma unroll
        for (int d = 32; d; d >>= 1) acc[o] += __shfl_xor(acc[o], d, 64);
    }
    if (lane == 0) {
#pragma unroll
        for (int o = 0; o < OUTD; ++o) out[row * OUTD + o] = acc[o] + bias[o];
    }
}

extern "C" void kernel_launch(void* const* d_in, const int* in_sizes, int n_in,
                              void* d_out, int out_size, void* d_ws, size_t ws_size,
                              hipStream_t stream) {
    const float* x  = (const float*)d_in[0];  // (1024, 784)
    const float* C0 = (const float*)d_in[1];  // (1, 512)
    const float* C1 = (const float*)d_in[2];  // (512, 512)
    const float* W  = (const float*)d_in[3];  // (512, 10)
    const float* b  = (const float*)d_in[4];  // (10,)
    float* M = (float*)d_ws;                  // 512*10 fp32 scratch

    compute_M<<<dim3(8), dim3(256), 0, stream>>>(C1, W, M);
    ssm_main<<<dim3(256), dim3(256), 0, stream>>>(x, C0, M, b, (float*)d_out);
}